// Round 3
// baseline (533.398 us; speedup 1.0000x reference)
//
#include <hip/hip_runtime.h>
#include <hip/hip_bf16.h>
#include <stdint.h>

// Problem constants
#define DIN   4096
#define DOUT  4096
#define RANK  16
#define NSUB  4
#define MTOT  8192            // B*S = 4*2048
#define LDK   4160            // 4096 + 64 sub-adapter cols; 4160 = 65*64
#define KTAIL 64              // NSUB*RANK
#define NV    80              // 64 sub_A rows + 4 gate rows + 12 zero pad
#define KTILES 65             // LDK / 64

typedef __attribute__((ext_vector_type(8)))  short    short8;   // 8 bf16 (4 VGPRs)
typedef __attribute__((ext_vector_type(4)))  float    floatx4;
typedef __attribute__((ext_vector_type(8)))  unsigned short ushort8;
typedef __attribute__((ext_vector_type(4)))  unsigned short ushort4v;

static __device__ __forceinline__ unsigned short f2bf(float f) {
    unsigned int u = __float_as_uint(f);
    unsigned int r = (u + 0x7FFFu + ((u >> 16) & 1u)) >> 16;   // RNE
    return (unsigned short)r;
}

static __device__ __forceinline__ void async_copy16(const unsigned short* g, unsigned short* l) {
    __builtin_amdgcn_global_load_lds(
        (const __attribute__((address_space(1))) unsigned int*)g,
        (__attribute__((address_space(3))) unsigned int*)l,
        16, 0, 0);
}

// ---------------------------------------------------------------------------
// Kernel 0: build Vc [NV][DIN] bf16: rows 0..63 = sub_A (flat [64][DIN]),
// rows 64..67 = sub_wgate, rows 68..79 = 0 (ws is poisoned 0xAA!).
// ---------------------------------------------------------------------------
__global__ __launch_bounds__(256) void build_v_kernel(
    const float* __restrict__ sub_wgate,
    const float* __restrict__ sub_A,
    unsigned short* __restrict__ Vc)
{
    const int t = threadIdx.x;
    const int row = blockIdx.x;      // 0..79
    const float* src = (row < 64) ? (sub_A + (size_t)row * DIN)
                     : (row < 68) ? (sub_wgate + (size_t)(row - 64) * DIN)
                     : nullptr;
#pragma unroll
    for (int i = 0; i < 4; ++i) {
        int c4 = t + 256 * i;          // float4 index, 0..1023
        ushort4v v;
        if (src) {
            float4 a = ((const float4*)src)[c4];
            v[0] = f2bf(a.x); v[1] = f2bf(a.y); v[2] = f2bf(a.z); v[3] = f2bf(a.w);
        } else {
            v[0] = v[1] = v[2] = v[3] = 0;
        }
        *(ushort4v*)(Vc + (size_t)row * DIN + c4 * 4) = v;
    }
}

// ---------------------------------------------------------------------------
// Kernel 1 (v2): fused build of X_cat [MTOT][LDK] bf16.  (unchanged)
// ---------------------------------------------------------------------------
#define BXK 256
#define LDA 264
__global__ __launch_bounds__(256) void build_x_kernel(
    const float* __restrict__ x,
    const unsigned short* __restrict__ Vc,
    unsigned short* __restrict__ Xc)
{
    __shared__ char smem[(16 + NV) * LDA * 2];           // 50688 B
    unsigned short* As = (unsigned short*)smem;          // [16][LDA]
    unsigned short* Bs = As + 16 * LDA;                  // [NV][LDA]
    float* Pp = (float*)smem;                            // [4][16][NV], reused

    const int t  = threadIdx.x;
    const int l  = t & 63;
    const int w  = t >> 6;        // wave = k-quarter
    const int m0 = blockIdx.x * 16;
    const int lane16 = l & 15;
    const int kq     = (l >> 4) * 8;

    floatx4 acc[5] = {};

    for (int cc = 0; cc < DIN; cc += BXK) {
        // stage x chunk [16][256]: fp32 -> bf16 -> LDS + global Xc (2 u8/thread)
#pragma unroll
        for (int i = 0; i < 2; ++i) {
            int u8 = t + 256 * i;        // 0..511
            int tr = u8 >> 5;            // 32 ushort8 per row
            int c8 = u8 & 31;
            const float4* src = (const float4*)(x + (size_t)(m0 + tr) * DIN + cc + c8 * 8);
            float4 a = src[0], b = src[1];
            ushort8 v;
            v[0] = f2bf(a.x); v[1] = f2bf(a.y); v[2] = f2bf(a.z); v[3] = f2bf(a.w);
            v[4] = f2bf(b.x); v[5] = f2bf(b.y); v[6] = f2bf(b.z); v[7] = f2bf(b.w);
            *(ushort8*)&As[tr * LDA + c8 * 8] = v;
            *(ushort8*)(Xc + (size_t)(m0 + tr) * LDK + cc + c8 * 8) = v;
        }
        // stage Vc chunk [80][256] (bf16, L2-resident): 10 u8/thread
#pragma unroll
        for (int i = 0; i < 10; ++i) {
            int idx = t + 256 * i;       // 0..2559
            int vr  = idx >> 5;
            int c8  = idx & 31;
            ushort8 v = *(const ushort8*)(Vc + (size_t)vr * DIN + cc + c8 * 8);
            *(ushort8*)&Bs[vr * LDA + c8 * 8] = v;
        }
        __syncthreads();

        // MFMA: wave w handles k-steps {2w, 2w+1} of the 8 in this chunk
#pragma unroll
        for (int s = 0; s < 2; ++s) {
            int ks = w * 2 + s;
            short8 af = *(const short8*)&As[lane16 * LDA + ks * 32 + kq];
#pragma unroll
            for (int n = 0; n < 5; ++n) {
                short8 bf = *(const short8*)&Bs[(n * 16 + lane16) * LDA + ks * 32 + kq];
                acc[n] = __builtin_amdgcn_mfma_f32_16x16x32_bf16(af, bf, acc[n], 0, 0, 0);
            }
        }
        __syncthreads();
    }

    // dump partial P (C/D layout: col=lane&15, row=(l>>4)*4+reg)
#pragma unroll
    for (int n = 0; n < 5; ++n)
#pragma unroll
        for (int r = 0; r < 4; ++r)
            Pp[(w * 16 + (l >> 4) * 4 + r) * NV + n * 16 + lane16] = acc[n][r];
    __syncthreads();

    // gated tail: 16 tokens x 64 cols, summing the 4 k-partials
#pragma unroll
    for (int i = 0; i < 4; ++i) {
        int v  = t + 256 * i;            // 0..1023
        int tr = v >> 6;
        int c  = v & 63;
        int j  = c >> 4;
        float ps = 0.f, gs = 0.f;
#pragma unroll
        for (int q = 0; q < 4; ++q) {
            ps += Pp[(q * 16 + tr) * NV + c];
            gs += Pp[(q * 16 + tr) * NV + 64 + j];
        }
        Xc[(size_t)(m0 + tr) * LDK + DIN + c] = f2bf(2.0f * fmaxf(gs, 0.f) * ps);
    }
}

// ---------------------------------------------------------------------------
// Kernel 2 (v2): build W_cat [DOUT][LDK] bf16 — streaming.  (unchanged)
// ---------------------------------------------------------------------------
__global__ __launch_bounds__(256) void build_w_kernel(
    const float* __restrict__ W,        // [DOUT][DIN]
    const float* __restrict__ base_A,   // [RANK][DIN]
    const float* __restrict__ base_B,   // [DOUT][RANK]
    const float* __restrict__ sub_B,    // [NSUB][DOUT][RANK]
    unsigned short* __restrict__ Wc)
{
    __shared__ float bBs[8 * RANK];

    const int t  = threadIdx.x;
    const int o0 = (blockIdx.x >> 2) * 8;
    const int cc = (blockIdx.x & 3) * 1024;
    const int q  = (cc >> 2) + t;        // float4 index into a DIN row

    if (t < 128) bBs[t] = 2.0f * base_B[(size_t)o0 * RANK + t];
    __syncthreads();

    float4 acc[8];
#pragma unroll
    for (int o = 0; o < 8; ++o)
        acc[o] = ((const float4*)(W + (size_t)(o0 + o) * DIN))[q];

#pragma unroll
    for (int r = 0; r < RANK; ++r) {
        float4 a = ((const float4*)(base_A + (size_t)r * DIN))[q];
#pragma unroll
        for (int o = 0; o < 8; ++o) {
            float s = bBs[o * RANK + r];
            acc[o].x += s * a.x; acc[o].y += s * a.y;
            acc[o].z += s * a.z; acc[o].w += s * a.w;
        }
    }

#pragma unroll
    for (int o = 0; o < 8; ++o) {
        ushort4v v;
        v[0] = f2bf(acc[o].x); v[1] = f2bf(acc[o].y);
        v[2] = f2bf(acc[o].z); v[3] = f2bf(acc[o].w);
        *(ushort4v*)(Wc + (size_t)(o0 + o) * LDK + q * 4) = v;
    }

    // tail: one col-chunk per o-group writes the 8 x 64 sub_B cols
    if ((blockIdx.x & 3) == 0) {
#pragma unroll
        for (int i = 0; i < 2; ++i) {
            int v = t + 256 * i;             // 0..511
            int o = v >> 6;
            int c = v & 63;
            int j = c >> 4;
            int r = c & 15;
            float s = sub_B[((size_t)j * DOUT + (o0 + o)) * RANK + r];
            Wc[(size_t)(o0 + o) * LDK + DIN + c] = f2bf(s);
        }
    }
}

// ---------------------------------------------------------------------------
// Kernel 3 (v5): out = X_cat @ W_cat^T + bias — 256x256, BK=64, 8 waves.
// v5 = v4's addressing (compile-time parity, base+imm ds_reads, k-outer MFMA)
//      + the strict m201 phase discipline restored:
//      per phase: [ds_reads][stage][s_barrier][lgkmcnt(0)+sched_barrier(0)]
//                 [setprio(1) pure-MFMA burst setprio(0)][s_barrier].
//      8 barriers/tile. Waves drift through the DS queue and stagger their
//      MFMA bursts (T3 regime); setprio now has a role-split to arbitrate (T5).
// Region overwrite proof (unchanged from v4): every ds_read is drained by its
// wave's lgkm0 BEFORE that wave reaches the phase-close barrier; every
// re-stage issues AFTER that barrier:
//   A1(t+1)->buf^1 staged P1 (last read: t-1 P3 by wm1, drained t-1.P3 lgkm0)
//   B0,B1(t+2)->buf staged P3 (last read: P2 bb j23, drained P2 lgkm0)
//   A0(t+2)->buf    staged P4 (last read: P3 af mh1 by wm0, drained P3 lgkm0)
// vmcnt(6) once per tile (P4): drains A1(t+1) + older; {B0,B1,A0}(t+2) stay
// in flight. Epilogue: vmcnt(0) when t+2==KTILES; tile 64 no stage/wait.
// ---------------------------------------------------------------------------
#define BARM() asm volatile("s_barrier" ::: "memory")
#define LGKM0() do { asm volatile("s_waitcnt lgkmcnt(0)" ::: "memory"); \
                     __builtin_amdgcn_sched_barrier(0); } while (0)

#define LDA_(B,MH,I,S) (*(const short8*)((const char*)lds + (B)*32768 + (MH)*8192 + (I)*2048 + (aBy ^ ((S)*64))))
#define LDB_(B,J,S)    (*(const short8*)((const char*)lds + 65536 + (B)*32768 + (J)*2048 + (bBy ^ ((S)*64))))

#define STG(P, DST) do { async_copy16((P), (DST)); \
                         async_copy16((P) + (size_t)64 * LDK, (DST) + 4096); } while (0)
#define STAGE_A0(P,B) STG((P), &lds[(B)*16384 + tid*8])
#define STAGE_A1(P,B) STG((P), &lds[(B)*16384 + 8192 + tid*8])
#define STAGE_B0(P,B) STG((P), &lds[32768 + (B)*16384 + tid*8])
#define STAGE_B1(P,B) STG((P), &lds[32768 + (B)*16384 + 8192 + tid*8])

#define MFMA_HALF(MH, JLO) do { \
    _Pragma("unroll") for (int s_ = 0; s_ < 2; ++s_) \
    _Pragma("unroll") for (int i_ = 0; i_ < 4; ++i_) \
    _Pragma("unroll") for (int jj_ = 0; jj_ < 2; ++jj_) \
        acc[(MH)*4+i_][(JLO)+jj_] = __builtin_amdgcn_mfma_f32_16x16x32_bf16( \
            af[i_][s_], bb[(JLO)+jj_][s_], acc[(MH)*4+i_][(JLO)+jj_], 0, 0, 0); \
} while (0)

#define TILE_BODY(T, CUR) do { \
    /* P1: reads af[mh0](8) + bb[j01](4); stage A1(T+1) -> buf CUR^1 */ \
    _Pragma("unroll") for (int i_ = 0; i_ < 4; ++i_) { \
        af[i_][0] = LDA_(CUR, 0, i_, 0); af[i_][1] = LDA_(CUR, 0, i_, 1); } \
    _Pragma("unroll") for (int j_ = 0; j_ < 2; ++j_) { \
        bb[j_][0] = LDB_(CUR, j_, 0); bb[j_][1] = LDB_(CUR, j_, 1); } \
    if ((T) + 1 < KTILES) { STAGE_A1(pA1, (CUR) ^ 1); } \
    pA1 += 64; \
    BARM(); LGKM0(); \
    __builtin_amdgcn_s_setprio(1); MFMA_HALF(0, 0); __builtin_amdgcn_s_setprio(0); \
    BARM(); \
    /* P2: reads bb[j23](4) */ \
    _Pragma("unroll") for (int j_ = 2; j_ < 4; ++j_) { \
        bb[j_][0] = LDB_(CUR, j_, 0); bb[j_][1] = LDB_(CUR, j_, 1); } \
    BARM(); LGKM0(); \
    __builtin_amdgcn_s_setprio(1); MFMA_HALF(0, 2); __builtin_amdgcn_s_setprio(0); \
    BARM(); \
    /* P3: reads af[mh1](8); stage B0,B1(T+2) -> buf CUR */ \
    _Pragma("unroll") for (int i_ = 0; i_ < 4; ++i_) { \
        af[i_][0] = LDA_(CUR, 1, i_, 0); af[i_][1] = LDA_(CUR, 1, i_, 1); } \
    if ((T) + 2 < KTILES) { STAGE_B0(pB0, CUR); STAGE_B1(pB1, CUR); } \
    pB0 += 64; pB1 += 64; \
    BARM(); LGKM0(); \
    __builtin_amdgcn_s_setprio(1); MFMA_HALF(1, 0); __builtin_amdgcn_s_setprio(0); \
    BARM(); \
    /* P4: no reads; stage A0(T+2) -> buf CUR; counted vmcnt at close */ \
    if ((T) + 2 < KTILES) { STAGE_A0(pA0, CUR); } \
    pA0 += 64; \
    BARM(); \
    __builtin_amdgcn_sched_barrier(0); \
    __builtin_amdgcn_s_setprio(1); MFMA_HALF(1, 2); __builtin_amdgcn_s_setprio(0); \
    if ((T) + 2 < KTILES)      { asm volatile("s_waitcnt vmcnt(6)" ::: "memory"); } \
    else if ((T) + 1 < KTILES) { asm volatile("s_waitcnt vmcnt(0)" ::: "memory"); } \
    BARM(); \
} while (0)

__global__ __launch_bounds__(512, 2) void gemm_kernel(
    const unsigned short* __restrict__ Xc,
    const unsigned short* __restrict__ Wc,
    const float* __restrict__ bias,
    float* __restrict__ out)
{
    __shared__ unsigned short lds[65536];   // 128 KiB

    const int tid = threadIdx.x;
    const int l   = tid & 63;
    const int wv  = tid >> 6;        // 0..7
    const int wm  = wv >> 2;         // 0..1
    const int wn  = wv & 3;          // 0..3
    const int lane16 = l & 15;
    const int g   = l >> 4;          // 0..3
    const int lx  = lane16 & 7;      // swizzle key

    // XCD-aware swizzle: 512 wgs, 8 XCDs, 64 contiguous per XCD (bijective)
    const int bid = blockIdx.x;
    const int wg  = (bid & 7) * 64 + (bid >> 3);
    const int m0  = (wg >> 4) * 256;   // 32 m-tiles
    const int n0  = (wg & 15) * 256;   // 16 n-tiles

    // per-lane ds_read byte bases (s=0); s=1 flips byte bit 6 (chunk^4)
    const int aBy = wm * 16384 + lane16 * 128 + ((g ^ lx) << 4);
    const int bBy = wn * 8192  + lane16 * 128 + ((g ^ lx) << 4);

    // staging source pointers (pre-swizzled global chunk), advance 128 B/tile
    const int r0 = tid >> 3;                 // 0..63
    const int c0 = (tid & 7) ^ (r0 & 7);
    const unsigned short* pA0 = Xc + (size_t)(m0 + r0) * LDK + c0 * 8;
    const unsigned short* pA1 = pA0 + (size_t)128 * LDK;
    const unsigned short* pB0 = Wc + (size_t)(n0 + r0) * LDK + c0 * 8;
    const unsigned short* pB1 = pB0 + (size_t)128 * LDK;

    floatx4 acc[8][4] = {};
    short8 af[4][2], bb[4][2];

    // prologue: tile0 all 4 halves -> buf0; tile1 {B0,B1,A0} -> buf1
    STAGE_B0(pB0, 0); STAGE_B1(pB1, 0); STAGE_A0(pA0, 0); STAGE_A1(pA1, 0);
    STAGE_B0(pB0 + 64, 1); STAGE_B1(pB1 + 64, 1); STAGE_A0(pA0 + 64, 1);
    pA1 += 64; pB0 += 128; pB1 += 128; pA0 += 128;
    asm volatile("s_waitcnt vmcnt(6)" ::: "memory");   // tile0's 8 loads landed
    BARM();

    for (int t = 0; t < KTILES - 1; t += 2) {
        TILE_BODY(t, 0);
        TILE_BODY(t + 1, 1);
    }
    TILE_BODY(KTILES - 1, 0);   // tile 64, parity 0; no staging, no vmcnt

    // epilogue: C/D layout col = lane&15, row = (lane>>4)*4 + reg
    const int row_l = g * 4;
#pragma unroll
    for (int j = 0; j < 4; ++j) {
        const int gcol = n0 + wn * 64 + j * 16 + lane16;
        const float bv = bias[gcol];
#pragma unroll
        for (int i = 0; i < 8; ++i) {
            const int grow = m0 + wm * 128 + i * 16 + row_l;
            size_t base = (size_t)grow * DOUT + gcol;
            out[base]            = acc[i][j][0] + bv;
            out[base + DOUT]     = acc[i][j][1] + bv;
            out[base + 2 * DOUT] = acc[i][j][2] + bv;
            out[base + 3 * DOUT] = acc[i][j][3] + bv;
        }
    }
}

// ---------------------------------------------------------------------------
extern "C" void kernel_launch(void* const* d_in, const int* in_sizes, int n_in,
                              void* d_out, int out_size, void* d_ws, size_t ws_size,
                              hipStream_t stream) {
    const float* x         = (const float*)d_in[0];
    const float* base_W    = (const float*)d_in[1];
    const float* base_b    = (const float*)d_in[2];
    const float* base_A    = (const float*)d_in[3];
    const float* base_B    = (const float*)d_in[4];
    const float* sub_wgate = (const float*)d_in[5];
    const float* sub_A     = (const float*)d_in[6];
    const float* sub_B     = (const float*)d_in[7];
    float* out = (float*)d_out;

    // workspace layout (bf16): X_cat [8192][4160], W_cat [4096][4160], Vc [80][4096]
    unsigned short* Xc = (unsigned short*)d_ws;
    unsigned short* Wc = Xc + (size_t)MTOT * LDK;
    unsigned short* Vc = Wc + (size_t)DOUT * LDK;

    build_v_kernel<<<NV, 256, 0, stream>>>(sub_wgate, sub_A, Vc);
    build_x_kernel<<<MTOT / 16, 256, 0, stream>>>(x, Vc, Xc);
    build_w_kernel<<<(DOUT / 8) * 4, 256, 0, stream>>>(base_W, base_A, base_B, sub_B, Wc);
    gemm_kernel<<<dim3(DOUT / 256 * (MTOT / 256)), 512, 0, stream>>>(Xc, Wc, base_b, out);
}

// Round 4
// 530.328 us; speedup vs baseline: 1.0058x; 1.0058x over previous
//
#include <hip/hip_runtime.h>
#include <hip/hip_bf16.h>
#include <stdint.h>

// Problem constants
#define DIN   4096
#define DOUT  4096
#define RANK  16
#define NSUB  4
#define MTOT  8192            // B*S = 4*2048
#define LDK   4160            // 4096 + 64 sub-adapter cols; 4160 = 65*64
#define KTAIL 64              // NSUB*RANK
#define NV    80              // 64 sub_A rows + 4 gate rows + 12 zero pad
#define KTILES 65             // LDK / 64

typedef __attribute__((ext_vector_type(8)))  short    short8;   // 8 bf16 (4 VGPRs)
typedef __attribute__((ext_vector_type(4)))  float    floatx4;
typedef __attribute__((ext_vector_type(8)))  unsigned short ushort8;
typedef __attribute__((ext_vector_type(4)))  unsigned short ushort4v;

static __device__ __forceinline__ unsigned short f2bf(float f) {
    unsigned int u = __float_as_uint(f);
    unsigned int r = (u + 0x7FFFu + ((u >> 16) & 1u)) >> 16;   // RNE
    return (unsigned short)r;
}

static __device__ __forceinline__ void async_copy16(const unsigned short* g, unsigned short* l) {
    __builtin_amdgcn_global_load_lds(
        (const __attribute__((address_space(1))) unsigned int*)g,
        (__attribute__((address_space(3))) unsigned int*)l,
        16, 0, 0);
}

// ---------------------------------------------------------------------------
// Kernel 0: build Vc [NV][DIN] bf16: rows 0..63 = sub_A (flat [64][DIN]),
// rows 64..67 = sub_wgate, rows 68..79 = 0 (ws is poisoned 0xAA!).
// ---------------------------------------------------------------------------
__global__ __launch_bounds__(256) void build_v_kernel(
    const float* __restrict__ sub_wgate,
    const float* __restrict__ sub_A,
    unsigned short* __restrict__ Vc)
{
    const int t = threadIdx.x;
    const int row = blockIdx.x;      // 0..79
    const float* src = (row < 64) ? (sub_A + (size_t)row * DIN)
                     : (row < 68) ? (sub_wgate + (size_t)(row - 64) * DIN)
                     : nullptr;
#pragma unroll
    for (int i = 0; i < 4; ++i) {
        int c4 = t + 256 * i;          // float4 index, 0..1023
        ushort4v v;
        if (src) {
            float4 a = ((const float4*)src)[c4];
            v[0] = f2bf(a.x); v[1] = f2bf(a.y); v[2] = f2bf(a.z); v[3] = f2bf(a.w);
        } else {
            v[0] = v[1] = v[2] = v[3] = 0;
        }
        *(ushort4v*)(Vc + (size_t)row * DIN + c4 * 4) = v;
    }
}

// ---------------------------------------------------------------------------
// Kernel 1a (NEW): convert_x — pure streaming fp32 -> bf16 of x into
// Xc[:, 0:4096]. One row per (block, i); thread t covers cols t*16..t*16+15.
// 64 B/thread loads, 32 B/thread stores, fully coalesced. No LDS, no barriers.
// ---------------------------------------------------------------------------
__global__ __launch_bounds__(256) void convert_x_kernel(
    const float* __restrict__ x,
    unsigned short* __restrict__ Xc)
{
    const int t = threadIdx.x;
    const int b = blockIdx.x;        // 0..2047, 4 rows each
#pragma unroll
    for (int i = 0; i < 4; ++i) {
        const int row = b * 4 + i;
        const float4* s = (const float4*)(x + (size_t)row * DIN + t * 16);
        float4 a = s[0], b4 = s[1], c = s[2], d = s[3];
        ushort8 v0, v1;
        v0[0] = f2bf(a.x);  v0[1] = f2bf(a.y);  v0[2] = f2bf(a.z);  v0[3] = f2bf(a.w);
        v0[4] = f2bf(b4.x); v0[5] = f2bf(b4.y); v0[6] = f2bf(b4.z); v0[7] = f2bf(b4.w);
        v1[0] = f2bf(c.x);  v1[1] = f2bf(c.y);  v1[2] = f2bf(c.z);  v1[3] = f2bf(c.w);
        v1[4] = f2bf(d.x);  v1[5] = f2bf(d.y);  v1[6] = f2bf(d.z);  v1[7] = f2bf(d.w);
        unsigned short* o = Xc + (size_t)row * LDK + t * 16;
        *(ushort8*)o       = v0;
        *(ushort8*)(o + 8) = v1;
    }
}

// ---------------------------------------------------------------------------
// Kernel 1b (NEW): xtail — P[32 tok][80] = Xc_bf16 @ Vc^T (MFMA, fp32 acc),
// then Xc[tok][4096+c] = bf16(2 * relu(P[tok][64+c>>4]) * P[tok][c]).
// Grid 256 (32 tokens/block), 256 thr = 4 waves, k-split 4 (each wave owns
// k-steps {2w,2w+1} of every 256-col chunk), LDS partial reduce at the end.
// Staging: global_load_lds x16B, double-buffered, counted vmcnt(14) (never 0
// mid-loop). XOR swizzle: LDS(row,chunk16) holds global chunk (chunk^(row&7));
// reader applies same XOR -> 2-way residual conflicts (free). Source is
// pre-swizzled, LDS dest linear (rule #21: both-sides-or-neither).
// Vc rows 68..79 are zeros (build_v) so the padded reads are benign.
// ---------------------------------------------------------------------------
#define XS_STG(P) do { unsigned short* d_ = &lds[(P)*8192 + t*8]; \
    _Pragma("unroll") for (int i_ = 0; i_ < 4; ++i_) \
        async_copy16(pXs + (size_t)(8*i_) * LDK, d_ + i_*2048); } while (0)
#define VS_STG(P) do { unsigned short* d_ = &lds[16384 + (P)*20480 + t*8]; \
    _Pragma("unroll") for (int i_ = 0; i_ < 10; ++i_) \
        async_copy16(pVs + (size_t)(8*i_) * DIN, d_ + i_*2048); } while (0)

#define XT_MM(P, KB) do { \
    short8 a0_ = *(const short8*)((const char*)lds + (P)*16384 + aB + (KB)); \
    short8 a1_ = *(const short8*)((const char*)lds + (P)*16384 + 8192 + aB + (KB)); \
    _Pragma("unroll") for (int n_ = 0; n_ < 5; ++n_) { \
        short8 b_ = *(const short8*)((const char*)lds + 32768 + (P)*40960 + n_*8192 + aB + (KB)); \
        acc[0][n_] = __builtin_amdgcn_mfma_f32_16x16x32_bf16(a0_, b_, acc[0][n_], 0, 0, 0); \
        acc[1][n_] = __builtin_amdgcn_mfma_f32_16x16x32_bf16(a1_, b_, acc[1][n_], 0, 0, 0); } \
} while (0)

#define XT_ITER(P, WN, DOSTG) do { \
    asm volatile("s_waitcnt vmcnt(" #WN ")" ::: "memory"); \
    asm volatile("s_barrier" ::: "memory"); \
    XT_MM(P, kb0); \
    XT_MM(P, kb1); \
    asm volatile("s_barrier" ::: "memory"); \
    if (DOSTG) { XS_STG(P); VS_STG(P); } \
    pXs += 256; pVs += 256; \
} while (0)

__global__ __launch_bounds__(256) void xtail_kernel(
    const unsigned short* __restrict__ Vc,
    unsigned short* __restrict__ Xc)
{
    __shared__ __align__(16) unsigned short lds[57344]; // Xs[2][32][256] @0 | Vs[2][80][256] @u16384

    const int t = threadIdx.x;
    const int l = t & 63;
    const int w = t >> 6;            // k-quarter 0..3
    const int lane16 = l & 15;
    const int g = l >> 4;            // 0..3
    const int lx2 = lane16 & 7;
    const int m0 = blockIdx.x * 32;

    // staging source (pre-swizzled 16B-chunk), advances 512 B/chunk
    const int srow = t >> 5;                       // 0..7
    const int scl  = (t & 31) ^ (srow & 7);
    const unsigned short* pXs = Xc + (size_t)(m0 + srow) * LDK + scl * 8;
    const unsigned short* pVs = Vc + (size_t)srow * DIN + scl * 8;

    // ds_read byte k-offsets (loop-invariant): phys chunk = (ks*4+g) ^ lx2
    const int hk  = lx2 >> 2;
    const int gx  = g ^ (lx2 & 3);
    const int kb0 = (((2*w + 0) ^ hk) * 4 + gx) * 16;
    const int kb1 = (((2*w + 1) ^ hk) * 4 + gx) * 16;
    const int aB  = lane16 * 512;

    floatx4 acc[2][5] = {};

    // prologue: chunks 0,1
    XS_STG(0); VS_STG(0); pXs += 256; pVs += 256;
    XS_STG(1); VS_STG(1); pXs += 256; pVs += 256;

#pragma unroll 1
    for (int c = 0; c < 14; c += 2) {   // chunks 0..13, staging 2..15
        XT_ITER(0, 14, 1);
        XT_ITER(1, 14, 1);
    }
    XT_ITER(0, 14, 0);                  // chunk 14
    XT_ITER(1, 0, 0);                   // chunk 15 (drain)

    // partial-P reduce: Pp[4][32][80] fp32 (40960 B, reuses LDS)
    float* Pp = (float*)lds;
#pragma unroll
    for (int tm = 0; tm < 2; ++tm)
#pragma unroll
        for (int n = 0; n < 5; ++n)
#pragma unroll
            for (int r = 0; r < 4; ++r)
                Pp[((w * 32) + tm * 16 + (l >> 4) * 4 + r) * 80 + n * 16 + lane16] = acc[tm][n][r];
    __syncthreads();

    // gated tail: 32 tokens x 64 cols
#pragma unroll
    for (int i = 0; i < 8; ++i) {
        int v  = t + 256 * i;            // 0..2047
        int tr = v >> 6;                 // 0..31
        int c  = v & 63;
        int j  = c >> 4;
        float ps = 0.f, gs = 0.f;
#pragma unroll
        for (int q = 0; q < 4; ++q) {
            ps += Pp[(q * 32 + tr) * 80 + c];
            gs += Pp[(q * 32 + tr) * 80 + 64 + j];
        }
        Xc[(size_t)(m0 + tr) * LDK + DIN + c] = f2bf(2.0f * fmaxf(gs, 0.f) * ps);
    }
}

// ---------------------------------------------------------------------------
// Kernel 2 (v2): build W_cat [DOUT][LDK] bf16 — streaming.  (unchanged)
// ---------------------------------------------------------------------------
__global__ __launch_bounds__(256) void build_w_kernel(
    const float* __restrict__ W,        // [DOUT][DIN]
    const float* __restrict__ base_A,   // [RANK][DIN]
    const float* __restrict__ base_B,   // [DOUT][RANK]
    const float* __restrict__ sub_B,    // [NSUB][DOUT][RANK]
    unsigned short* __restrict__ Wc)
{
    __shared__ float bBs[8 * RANK];

    const int t  = threadIdx.x;
    const int o0 = (blockIdx.x >> 2) * 8;
    const int cc = (blockIdx.x & 3) * 1024;
    const int q  = (cc >> 2) + t;        // float4 index into a DIN row

    if (t < 128) bBs[t] = 2.0f * base_B[(size_t)o0 * RANK + t];
    __syncthreads();

    float4 acc[8];
#pragma unroll
    for (int o = 0; o < 8; ++o)
        acc[o] = ((const float4*)(W + (size_t)(o0 + o) * DIN))[q];

#pragma unroll
    for (int r = 0; r < RANK; ++r) {
        float4 a = ((const float4*)(base_A + (size_t)r * DIN))[q];
#pragma unroll
        for (int o = 0; o < 8; ++o) {
            float s = bBs[o * RANK + r];
            acc[o].x += s * a.x; acc[o].y += s * a.y;
            acc[o].z += s * a.z; acc[o].w += s * a.w;
        }
    }

#pragma unroll
    for (int o = 0; o < 8; ++o) {
        ushort4v v;
        v[0] = f2bf(acc[o].x); v[1] = f2bf(acc[o].y);
        v[2] = f2bf(acc[o].z); v[3] = f2bf(acc[o].w);
        *(ushort4v*)(Wc + (size_t)(o0 + o) * LDK + q * 4) = v;
    }

    // tail: one col-chunk per o-group writes the 8 x 64 sub_B cols
    if ((blockIdx.x & 3) == 0) {
#pragma unroll
        for (int i = 0; i < 2; ++i) {
            int v = t + 256 * i;             // 0..511
            int o = v >> 6;
            int c = v & 63;
            int j = c >> 4;
            int r = c & 15;
            float s = sub_B[((size_t)j * DOUT + (o0 + o)) * RANK + r];
            Wc[(size_t)(o0 + o) * LDK + DIN + c] = f2bf(s);
        }
    }
}

// ---------------------------------------------------------------------------
// Kernel 3 (v4, VERBATIM from R2 — measured 252 µs): out = Xc @ Wc^T + bias.
// 256x256, BK=64, 8 waves; relaxed schedule (compiler fine-grained lgkmcnt),
// 4 barriers/tile, counted vmcnt(6), XOR LDS swizzle, XCD swizzle.
// ---------------------------------------------------------------------------
#define BARM() asm volatile("s_barrier" ::: "memory")

#define LDA_(B,MH,I,S) (*(const short8*)((const char*)lds + (B)*32768 + (MH)*8192 + (I)*2048 + (aBy ^ ((S)*64))))
#define LDB_(B,J,S)    (*(const short8*)((const char*)lds + 65536 + (B)*32768 + (J)*2048 + (bBy ^ ((S)*64))))

#define STG(P, DST) do { async_copy16((P), (DST)); \
                         async_copy16((P) + (size_t)64 * LDK, (DST) + 4096); } while (0)
#define STAGE_A0(P,B) STG((P), &lds[(B)*16384 + tid*8])
#define STAGE_A1(P,B) STG((P), &lds[(B)*16384 + 8192 + tid*8])
#define STAGE_B0(P,B) STG((P), &lds[32768 + (B)*16384 + tid*8])
#define STAGE_B1(P,B) STG((P), &lds[32768 + (B)*16384 + 8192 + tid*8])

#define MFMA_HALF(MH, JLO) do { \
    _Pragma("unroll") for (int s_ = 0; s_ < 2; ++s_) \
    _Pragma("unroll") for (int i_ = 0; i_ < 4; ++i_) \
    _Pragma("unroll") for (int jj_ = 0; jj_ < 2; ++jj_) \
        acc[(MH)*4+i_][(JLO)+jj_] = __builtin_amdgcn_mfma_f32_16x16x32_bf16( \
            af[i_][s_], bb[(JLO)+jj_][s_], acc[(MH)*4+i_][(JLO)+jj_], 0, 0, 0); \
} while (0)

#define TILE_BODY(T, CUR) do { \
    /* P1: af[mh0] (8) + bb[j0,1] (4); stage A1(T+1) -> buf CUR^1 */ \
    _Pragma("unroll") for (int i_ = 0; i_ < 4; ++i_) { \
        af[i_][0] = LDA_(CUR, 0, i_, 0); af[i_][1] = LDA_(CUR, 0, i_, 1); } \
    _Pragma("unroll") for (int j_ = 0; j_ < 2; ++j_) { \
        bb[j_][0] = LDB_(CUR, j_, 0); bb[j_][1] = LDB_(CUR, j_, 1); } \
    if ((T) + 1 < KTILES) { STAGE_A1(pA1, (CUR) ^ 1); } \
    pA1 += 64; \
    __builtin_amdgcn_s_setprio(1); MFMA_HALF(0, 0); __builtin_amdgcn_s_setprio(0); \
    BARM(); \
    /* P2: bb[j2,3] (4) */ \
    _Pragma("unroll") for (int j_ = 2; j_ < 4; ++j_) { \
        bb[j_][0] = LDB_(CUR, j_, 0); bb[j_][1] = LDB_(CUR, j_, 1); } \
    __builtin_amdgcn_s_setprio(1); MFMA_HALF(0, 2); __builtin_amdgcn_s_setprio(0); \
    BARM(); \
    /* P3: af[mh1] (8); stage B0,B1(T+2); mid-barrier; stage A0(T+2); 32 MFMA */ \
    _Pragma("unroll") for (int i_ = 0; i_ < 4; ++i_) { \
        af[i_][0] = LDA_(CUR, 1, i_, 0); af[i_][1] = LDA_(CUR, 1, i_, 1); } \
    if ((T) + 2 < KTILES) { STAGE_B0(pB0, CUR); STAGE_B1(pB1, CUR); } \
    pB0 += 64; pB1 += 64; \
    BARM(); \
    if ((T) + 2 < KTILES) { STAGE_A0(pA0, CUR); } \
    pA0 += 64; \
    __builtin_amdgcn_s_setprio(1); MFMA_HALF(1, 0); MFMA_HALF(1, 2); __builtin_amdgcn_s_setprio(0); \
    if ((T) + 2 < KTILES)      { asm volatile("s_waitcnt vmcnt(6)" ::: "memory"); } \
    else if ((T) + 1 < KTILES) { asm volatile("s_waitcnt vmcnt(0)" ::: "memory"); } \
    BARM(); \
} while (0)

__global__ __launch_bounds__(512, 2) void gemm_kernel(
    const unsigned short* __restrict__ Xc,
    const unsigned short* __restrict__ Wc,
    const float* __restrict__ bias,
    float* __restrict__ out)
{
    __shared__ unsigned short lds[65536];   // 128 KiB

    const int tid = threadIdx.x;
    const int l   = tid & 63;
    const int wv  = tid >> 6;        // 0..7
    const int wm  = wv >> 2;         // 0..1
    const int wn  = wv & 3;          // 0..3
    const int lane16 = l & 15;
    const int g   = l >> 4;          // 0..3
    const int lx  = lane16 & 7;      // swizzle key

    // XCD-aware swizzle: 512 wgs, 8 XCDs, 64 contiguous per XCD (bijective)
    const int bid = blockIdx.x;
    const int wg  = (bid & 7) * 64 + (bid >> 3);
    const int m0  = (wg >> 4) * 256;   // 32 m-tiles
    const int n0  = (wg & 15) * 256;   // 16 n-tiles

    // per-lane ds_read byte bases (s=0); s=1 flips byte bit 6 (chunk^4)
    const int aBy = wm * 16384 + lane16 * 128 + ((g ^ lx) << 4);
    const int bBy = wn * 8192  + lane16 * 128 + ((g ^ lx) << 4);

    // staging source pointers (pre-swizzled global chunk), advance 128 B/tile
    const int r0 = tid >> 3;                 // 0..63
    const int c0 = (tid & 7) ^ (r0 & 7);
    const unsigned short* pA0 = Xc + (size_t)(m0 + r0) * LDK + c0 * 8;
    const unsigned short* pA1 = pA0 + (size_t)128 * LDK;
    const unsigned short* pB0 = Wc + (size_t)(n0 + r0) * LDK + c0 * 8;
    const unsigned short* pB1 = pB0 + (size_t)128 * LDK;

    floatx4 acc[8][4] = {};
    short8 af[4][2], bb[4][2];

    // prologue: tile0 all 4 halves -> buf0; tile1 {B0,B1,A0} -> buf1
    STAGE_B0(pB0, 0); STAGE_B1(pB1, 0); STAGE_A0(pA0, 0); STAGE_A1(pA1, 0);
    STAGE_B0(pB0 + 64, 1); STAGE_B1(pB1 + 64, 1); STAGE_A0(pA0 + 64, 1);
    pA1 += 64; pB0 += 128; pB1 += 128; pA0 += 128;
    asm volatile("s_waitcnt vmcnt(6)" ::: "memory");   // tile0's 8 loads landed
    BARM();

    for (int t = 0; t < KTILES - 1; t += 2) {
        TILE_BODY(t, 0);
        TILE_BODY(t + 1, 1);
    }
    TILE_BODY(KTILES - 1, 0);   // tile 64, parity 0; no staging, no vmcnt

    // epilogue: C/D layout col = lane&15, row = (lane>>4)*4 + reg
    const int row_l = g * 4;
#pragma unroll
    for (int j = 0; j < 4; ++j) {
        const int gcol = n0 + wn * 64 + j * 16 + lane16;
        const float bv = bias[gcol];
#pragma unroll
        for (int i = 0; i < 8; ++i) {
            const int grow = m0 + wm * 128 + i * 16 + row_l;
            size_t base = (size_t)grow * DOUT + gcol;
            out[base]            = acc[i][j][0] + bv;
            out[base + DOUT]     = acc[i][j][1] + bv;
            out[base + 2 * DOUT] = acc[i][j][2] + bv;
            out[base + 3 * DOUT] = acc[i][j][3] + bv;
        }
    }
}

// ---------------------------------------------------------------------------
extern "C" void kernel_launch(void* const* d_in, const int* in_sizes, int n_in,
                              void* d_out, int out_size, void* d_ws, size_t ws_size,
                              hipStream_t stream) {
    const float* x         = (const float*)d_in[0];
    const float* base_W    = (const float*)d_in[1];
    const float* base_b    = (const float*)d_in[2];
    const float* base_A    = (const float*)d_in[3];
    const float* base_B    = (const float*)d_in[4];
    const float* sub_wgate = (const float*)d_in[5];
    const float* sub_A     = (const float*)d_in[6];
    const float* sub_B     = (const float*)d_in[7];
    float* out = (float*)d_out;

    // workspace layout (bf16): X_cat [8192][4160], W_cat [4096][4160], Vc [80][4096]
    unsigned short* Xc = (unsigned short*)d_ws;
    unsigned short* Wc = Xc + (size_t)MTOT * LDK;
    unsigned short* Vc = Wc + (size_t)DOUT * LDK;

    build_v_kernel<<<NV, 256, 0, stream>>>(sub_wgate, sub_A, Vc);
    convert_x_kernel<<<MTOT / 4, 256, 0, stream>>>(x, Xc);
    xtail_kernel<<<MTOT / 32, 256, 0, stream>>>(Vc, Xc);
    build_w_kernel<<<(DOUT / 8) * 4, 256, 0, stream>>>(base_W, base_A, base_B, sub_B, Wc);
    gemm_kernel<<<dim3(DOUT / 256 * (MTOT / 256)), 512, 0, stream>>>(Xc, Wc, base_b, out);
}

// Round 5
// 528.376 us; speedup vs baseline: 1.0095x; 1.0037x over previous
//
#include <hip/hip_runtime.h>
#include <hip/hip_bf16.h>
#include <stdint.h>

// Problem constants
#define DIN   4096
#define DOUT  4096
#define RANK  16
#define NSUB  4
#define MTOT  8192            // B*S = 4*2048
#define LDK   4160            // 4096 + 64 sub-adapter cols; 4160 = 65*64
#define KTAIL 64              // NSUB*RANK
#define NV    80              // 64 sub_A rows + 4 gate rows + 12 zero pad
#define KTILES 65             // LDK / 64

typedef __attribute__((ext_vector_type(8)))  short    short8;   // 8 bf16 (4 VGPRs)
typedef __attribute__((ext_vector_type(4)))  float    floatx4;
typedef __attribute__((ext_vector_type(8)))  unsigned short ushort8;
typedef __attribute__((ext_vector_type(4)))  unsigned short ushort4v;

static __device__ __forceinline__ unsigned short f2bf(float f) {
    unsigned int u = __float_as_uint(f);
    unsigned int r = (u + 0x7FFFu + ((u >> 16) & 1u)) >> 16;   // RNE
    return (unsigned short)r;
}

static __device__ __forceinline__ void async_copy16(const unsigned short* g, unsigned short* l) {
    __builtin_amdgcn_global_load_lds(
        (const __attribute__((address_space(1))) unsigned int*)g,
        (__attribute__((address_space(3))) unsigned int*)l,
        16, 0, 0);
}

// ---------------------------------------------------------------------------
// Kernel P (fused prep): block-range dispatch, bodies verbatim from R4.
//   blocks [0,2048):    convert_x — fp32 x -> bf16 Xc[:, 0:4096] (4 rows/blk)
//   blocks [2048,2128): build_v   — Vc rows (sub_A flat, sub_wgate, zero pad)
//   blocks [2128,4176): build_w   — Wc = bf16(W + 2*base_B@base_A) | sub_B tail
// ---------------------------------------------------------------------------
__global__ __launch_bounds__(256) void prep_kernel(
    const float* __restrict__ x,
    unsigned short* __restrict__ Xc,
    const float* __restrict__ sub_wgate,
    const float* __restrict__ sub_A,
    unsigned short* __restrict__ Vc,
    const float* __restrict__ W,        // [DOUT][DIN]
    const float* __restrict__ base_A,   // [RANK][DIN]
    const float* __restrict__ base_B,   // [DOUT][RANK]
    const float* __restrict__ sub_B,    // [NSUB][DOUT][RANK]
    unsigned short* __restrict__ Wc)
{
    __shared__ float bBs[8 * RANK];
    const int t = threadIdx.x;

    if (blockIdx.x < 2048) {
        // ---- convert_x ----
        const int b = blockIdx.x;
#pragma unroll
        for (int i = 0; i < 4; ++i) {
            const int row = b * 4 + i;
            const float4* s = (const float4*)(x + (size_t)row * DIN + t * 16);
            float4 a = s[0], b4 = s[1], c = s[2], d = s[3];
            ushort8 v0, v1;
            v0[0] = f2bf(a.x);  v0[1] = f2bf(a.y);  v0[2] = f2bf(a.z);  v0[3] = f2bf(a.w);
            v0[4] = f2bf(b4.x); v0[5] = f2bf(b4.y); v0[6] = f2bf(b4.z); v0[7] = f2bf(b4.w);
            v1[0] = f2bf(c.x);  v1[1] = f2bf(c.y);  v1[2] = f2bf(c.z);  v1[3] = f2bf(c.w);
            v1[4] = f2bf(d.x);  v1[5] = f2bf(d.y);  v1[6] = f2bf(d.z);  v1[7] = f2bf(d.w);
            unsigned short* o = Xc + (size_t)row * LDK + t * 16;
            *(ushort8*)o       = v0;
            *(ushort8*)(o + 8) = v1;
        }
    } else if (blockIdx.x < 2048 + NV) {
        // ---- build_v ----
        const int row = blockIdx.x - 2048;   // 0..79
        const float* src = (row < 64) ? (sub_A + (size_t)row * DIN)
                         : (row < 68) ? (sub_wgate + (size_t)(row - 64) * DIN)
                         : nullptr;
#pragma unroll
        for (int i = 0; i < 4; ++i) {
            int c4 = t + 256 * i;          // float4 index, 0..1023
            ushort4v v;
            if (src) {
                float4 a = ((const float4*)src)[c4];
                v[0] = f2bf(a.x); v[1] = f2bf(a.y); v[2] = f2bf(a.z); v[3] = f2bf(a.w);
            } else {
                v[0] = v[1] = v[2] = v[3] = 0;
            }
            *(ushort4v*)(Vc + (size_t)row * DIN + c4 * 4) = v;
        }
    } else {
        // ---- build_w ----
        const int wb = blockIdx.x - 2048 - NV;   // 0..2047
        const int o0 = (wb >> 2) * 8;
        const int cc = (wb & 3) * 1024;
        const int q  = (cc >> 2) + t;        // float4 index into a DIN row

        if (t < 128) bBs[t] = 2.0f * base_B[(size_t)o0 * RANK + t];
        __syncthreads();

        float4 acc[8];
#pragma unroll
        for (int o = 0; o < 8; ++o)
            acc[o] = ((const float4*)(W + (size_t)(o0 + o) * DIN))[q];

#pragma unroll
        for (int r = 0; r < RANK; ++r) {
            float4 a = ((const float4*)(base_A + (size_t)r * DIN))[q];
#pragma unroll
            for (int o = 0; o < 8; ++o) {
                float s = bBs[o * RANK + r];
                acc[o].x += s * a.x; acc[o].y += s * a.y;
                acc[o].z += s * a.z; acc[o].w += s * a.w;
            }
        }

#pragma unroll
        for (int o = 0; o < 8; ++o) {
            ushort4v v;
            v[0] = f2bf(acc[o].x); v[1] = f2bf(acc[o].y);
            v[2] = f2bf(acc[o].z); v[3] = f2bf(acc[o].w);
            *(ushort4v*)(Wc + (size_t)(o0 + o) * LDK + q * 4) = v;
        }

        if ((wb & 3) == 0) {
#pragma unroll
            for (int i = 0; i < 2; ++i) {
                int v = t + 256 * i;             // 0..511
                int o = v >> 6;
                int c = v & 63;
                int j = c >> 4;
                int r = c & 15;
                float s = sub_B[((size_t)j * DOUT + (o0 + o)) * RANK + r];
                Wc[(size_t)(o0 + o) * LDK + DIN + c] = f2bf(s);
            }
        }
    }
}

// ---------------------------------------------------------------------------
// Kernel 1b: xtail — P[32 tok][80] = Xc_bf16 @ Vc^T (MFMA, fp32 acc),
// then Xc[tok][4096+c] = bf16(2 * relu(P[tok][64+c>>4]) * P[tok][c]).
// (unchanged from R4)
// ---------------------------------------------------------------------------
#define XS_STG(P) do { unsigned short* d_ = &lds[(P)*8192 + t*8]; \
    _Pragma("unroll") for (int i_ = 0; i_ < 4; ++i_) \
        async_copy16(pXs + (size_t)(8*i_) * LDK, d_ + i_*2048); } while (0)
#define VS_STG(P) do { unsigned short* d_ = &lds[16384 + (P)*20480 + t*8]; \
    _Pragma("unroll") for (int i_ = 0; i_ < 10; ++i_) \
        async_copy16(pVs + (size_t)(8*i_) * DIN, d_ + i_*2048); } while (0)

#define XT_MM(P, KB) do { \
    short8 a0_ = *(const short8*)((const char*)lds + (P)*16384 + aB + (KB)); \
    short8 a1_ = *(const short8*)((const char*)lds + (P)*16384 + 8192 + aB + (KB)); \
    _Pragma("unroll") for (int n_ = 0; n_ < 5; ++n_) { \
        short8 b_ = *(const short8*)((const char*)lds + 32768 + (P)*40960 + n_*8192 + aB + (KB)); \
        acc[0][n_] = __builtin_amdgcn_mfma_f32_16x16x32_bf16(a0_, b_, acc[0][n_], 0, 0, 0); \
        acc[1][n_] = __builtin_amdgcn_mfma_f32_16x16x32_bf16(a1_, b_, acc[1][n_], 0, 0, 0); } \
} while (0)

#define XT_ITER(P, WN, DOSTG) do { \
    asm volatile("s_waitcnt vmcnt(" #WN ")" ::: "memory"); \
    asm volatile("s_barrier" ::: "memory"); \
    XT_MM(P, kb0); \
    XT_MM(P, kb1); \
    asm volatile("s_barrier" ::: "memory"); \
    if (DOSTG) { XS_STG(P); VS_STG(P); } \
    pXs += 256; pVs += 256; \
} while (0)

__global__ __launch_bounds__(256) void xtail_kernel(
    const unsigned short* __restrict__ Vc,
    unsigned short* __restrict__ Xc)
{
    __shared__ __align__(16) unsigned short lds[57344]; // Xs[2][32][256] | Vs[2][80][256]

    const int t = threadIdx.x;
    const int l = t & 63;
    const int w = t >> 6;            // k-quarter 0..3
    const int lane16 = l & 15;
    const int g = l >> 4;            // 0..3
    const int lx2 = lane16 & 7;
    const int m0 = blockIdx.x * 32;

    const int srow = t >> 5;                       // 0..7
    const int scl  = (t & 31) ^ (srow & 7);
    const unsigned short* pXs = Xc + (size_t)(m0 + srow) * LDK + scl * 8;
    const unsigned short* pVs = Vc + (size_t)srow * DIN + scl * 8;

    const int hk  = lx2 >> 2;
    const int gx  = g ^ (lx2 & 3);
    const int kb0 = (((2*w + 0) ^ hk) * 4 + gx) * 16;
    const int kb1 = (((2*w + 1) ^ hk) * 4 + gx) * 16;
    const int aB  = lane16 * 512;

    floatx4 acc[2][5] = {};

    XS_STG(0); VS_STG(0); pXs += 256; pVs += 256;
    XS_STG(1); VS_STG(1); pXs += 256; pVs += 256;

#pragma unroll 1
    for (int c = 0; c < 14; c += 2) {   // chunks 0..13, staging 2..15
        XT_ITER(0, 14, 1);
        XT_ITER(1, 14, 1);
    }
    XT_ITER(0, 14, 0);                  // chunk 14
    XT_ITER(1, 0, 0);                   // chunk 15 (drain)

    float* Pp = (float*)lds;
#pragma unroll
    for (int tm = 0; tm < 2; ++tm)
#pragma unroll
        for (int n = 0; n < 5; ++n)
#pragma unroll
            for (int r = 0; r < 4; ++r)
                Pp[((w * 32) + tm * 16 + (l >> 4) * 4 + r) * 80 + n * 16 + lane16] = acc[tm][n][r];
    __syncthreads();

#pragma unroll
    for (int i = 0; i < 8; ++i) {
        int v  = t + 256 * i;            // 0..2047
        int tr = v >> 6;                 // 0..31
        int c  = v & 63;
        int j  = c >> 4;
        float ps = 0.f, gs = 0.f;
#pragma unroll
        for (int q = 0; q < 4; ++q) {
            ps += Pp[(q * 32 + tr) * 80 + c];
            gs += Pp[(q * 32 + tr) * 80 + 64 + j];
        }
        Xc[(size_t)(m0 + tr) * LDK + DIN + c] = f2bf(2.0f * fmaxf(gs, 0.f) * ps);
    }
}

// ---------------------------------------------------------------------------
// Kernel 3 (v6): out = Xc @ Wc^T + bias — 256x256, BK=64, 8 waves.
// v6 vs v4: collapse 4 phases -> 2 barriers/tile, one big read block + one
// in-burst read-ahead, to cut the 4x-per-tile LDS-latency ramp (the ~1600
// cyc/tile slop identified in R4's accounting):
//   [pre-bar]  af(mh0) 8 + bb(all) 8 ds_reads; lgkm0; sched_barrier; BARRIER
//   [post-bar] stage A1(t+1)->buf^1, B0,B1(t+2)->buf  (regions provably
//              reader-free: bb drained pre-bar; buf^1-A1 consumed t-1);
//              setprio(1) 32 MFMA (mh0) setprio(0);
//              af(mh1) reads REUSING af regs (WAR ordered after mh0 burst);
//              stage A0(t+2) (same race class v4 ran green 3 rounds);
//              setprio(1) 32 MFMA (mh1, compiler lgkm-waits) setprio(0);
//              vmcnt(6); BARRIER
// Register-neutral vs v4 (af reuse keeps 64 frag VGPRs; acc 128 in AGPR).
// vmcnt stream (A1,B0,B1,A0 per tile; counted 6; epilogue 0) identical to v4.
// ---------------------------------------------------------------------------
#define BARM() asm volatile("s_barrier" ::: "memory")

#define LDA_(B,MH,I,S) (*(const short8*)((const char*)lds + (B)*32768 + (MH)*8192 + (I)*2048 + (aBy ^ ((S)*64))))
#define LDB_(B,J,S)    (*(const short8*)((const char*)lds + 65536 + (B)*32768 + (J)*2048 + (bBy ^ ((S)*64))))

#define STG(P, DST) do { async_copy16((P), (DST)); \
                         async_copy16((P) + (size_t)64 * LDK, (DST) + 4096); } while (0)
#define STAGE_A0(P,B) STG((P), &lds[(B)*16384 + tid*8])
#define STAGE_A1(P,B) STG((P), &lds[(B)*16384 + 8192 + tid*8])
#define STAGE_B0(P,B) STG((P), &lds[32768 + (B)*16384 + tid*8])
#define STAGE_B1(P,B) STG((P), &lds[32768 + (B)*16384 + 8192 + tid*8])

#define MFMA_HALF2(MH) do { \
    _Pragma("unroll") for (int s_ = 0; s_ < 2; ++s_) \
    _Pragma("unroll") for (int i_ = 0; i_ < 4; ++i_) \
    _Pragma("unroll") for (int j_ = 0; j_ < 4; ++j_) \
        acc[(MH)*4+i_][j_] = __builtin_amdgcn_mfma_f32_16x16x32_bf16( \
            af[i_][s_], bb[j_][s_], acc[(MH)*4+i_][j_], 0, 0, 0); \
} while (0)

#define TILE_BODY(T, CUR) do { \
    /* pre-barrier: af(mh0) + all bb; full drain; barrier */ \
    _Pragma("unroll") for (int i_ = 0; i_ < 4; ++i_) { \
        af[i_][0] = LDA_(CUR, 0, i_, 0); af[i_][1] = LDA_(CUR, 0, i_, 1); } \
    _Pragma("unroll") for (int j_ = 0; j_ < 4; ++j_) { \
        bb[j_][0] = LDB_(CUR, j_, 0); bb[j_][1] = LDB_(CUR, j_, 1); } \
    asm volatile("s_waitcnt lgkmcnt(0)" ::: "memory"); \
    __builtin_amdgcn_sched_barrier(0); \
    BARM(); \
    /* post-barrier: stages to reader-free regions; mh0 burst */ \
    if ((T) + 1 < KTILES) { STAGE_A1(pA1, (CUR) ^ 1); } \
    if ((T) + 2 < KTILES) { STAGE_B0(pB0, CUR); STAGE_B1(pB1, CUR); } \
    pA1 += 64; pB0 += 64; pB1 += 64; \
    __builtin_amdgcn_s_setprio(1); MFMA_HALF2(0); __builtin_amdgcn_s_setprio(0); \
    /* af(mh1) read-ahead reusing af regs; overlaps mh0 pipe drain */ \
    _Pragma("unroll") for (int i_ = 0; i_ < 4; ++i_) { \
        af[i_][0] = LDA_(CUR, 1, i_, 0); af[i_][1] = LDA_(CUR, 1, i_, 1); } \
    if ((T) + 2 < KTILES) { STAGE_A0(pA0, CUR); } \
    pA0 += 64; \
    __builtin_amdgcn_s_setprio(1); MFMA_HALF2(1); __builtin_amdgcn_s_setprio(0); \
    if ((T) + 2 < KTILES)      { asm volatile("s_waitcnt vmcnt(6)" ::: "memory"); } \
    else if ((T) + 1 < KTILES) { asm volatile("s_waitcnt vmcnt(0)" ::: "memory"); } \
    BARM(); \
} while (0)

__global__ __launch_bounds__(512, 2) void gemm_kernel(
    const unsigned short* __restrict__ Xc,
    const unsigned short* __restrict__ Wc,
    const float* __restrict__ bias,
    float* __restrict__ out)
{
    __shared__ unsigned short lds[65536];   // 128 KiB

    const int tid = threadIdx.x;
    const int l   = tid & 63;
    const int wv  = tid >> 6;        // 0..7
    const int wm  = wv >> 2;         // 0..1
    const int wn  = wv & 3;          // 0..3
    const int lane16 = l & 15;
    const int g   = l >> 4;          // 0..3
    const int lx  = lane16 & 7;      // swizzle key

    // XCD-aware swizzle: 512 wgs, 8 XCDs, 64 contiguous per XCD (bijective)
    const int bid = blockIdx.x;
    const int wg  = (bid & 7) * 64 + (bid >> 3);
    const int m0  = (wg >> 4) * 256;   // 32 m-tiles
    const int n0  = (wg & 15) * 256;   // 16 n-tiles

    // per-lane ds_read byte bases (s=0); s=1 flips byte bit 6 (chunk^4)
    const int aBy = wm * 16384 + lane16 * 128 + ((g ^ lx) << 4);
    const int bBy = wn * 8192  + lane16 * 128 + ((g ^ lx) << 4);

    // staging source pointers (pre-swizzled global chunk), advance 128 B/tile
    const int r0 = tid >> 3;                 // 0..63
    const int c0 = (tid & 7) ^ (r0 & 7);
    const unsigned short* pA0 = Xc + (size_t)(m0 + r0) * LDK + c0 * 8;
    const unsigned short* pA1 = pA0 + (size_t)128 * LDK;
    const unsigned short* pB0 = Wc + (size_t)(n0 + r0) * LDK + c0 * 8;
    const unsigned short* pB1 = pB0 + (size_t)128 * LDK;

    floatx4 acc[8][4] = {};
    short8 af[4][2], bb[4][2];

    // prologue: tile0 all 4 halves -> buf0; tile1 {B0,B1,A0} -> buf1
    STAGE_B0(pB0, 0); STAGE_B1(pB1, 0); STAGE_A0(pA0, 0); STAGE_A1(pA1, 0);
    STAGE_B0(pB0 + 64, 1); STAGE_B1(pB1 + 64, 1); STAGE_A0(pA0 + 64, 1);
    pA1 += 64; pB0 += 128; pB1 += 128; pA0 += 128;
    asm volatile("s_waitcnt vmcnt(6)" ::: "memory");   // tile0's 8 loads landed
    BARM();

    for (int t = 0; t < KTILES - 1; t += 2) {
        TILE_BODY(t, 0);
        TILE_BODY(t + 1, 1);
    }
    TILE_BODY(KTILES - 1, 0);   // tile 64, parity 0; no staging, no vmcnt

    // epilogue: C/D layout col = lane&15, row = (lane>>4)*4 + reg
    const int row_l = g * 4;
#pragma unroll
    for (int j = 0; j < 4; ++j) {
        const int gcol = n0 + wn * 64 + j * 16 + lane16;
        const float bv = bias[gcol];
#pragma unroll
        for (int i = 0; i < 8; ++i) {
            const int grow = m0 + wm * 128 + i * 16 + row_l;
            size_t base = (size_t)grow * DOUT + gcol;
            out[base]            = acc[i][j][0] + bv;
            out[base + DOUT]     = acc[i][j][1] + bv;
            out[base + 2 * DOUT] = acc[i][j][2] + bv;
            out[base + 3 * DOUT] = acc[i][j][3] + bv;
        }
    }
}

// ---------------------------------------------------------------------------
extern "C" void kernel_launch(void* const* d_in, const int* in_sizes, int n_in,
                              void* d_out, int out_size, void* d_ws, size_t ws_size,
                              hipStream_t stream) {
    const float* x         = (const float*)d_in[0];
    const float* base_W    = (const float*)d_in[1];
    const float* base_b    = (const float*)d_in[2];
    const float* base_A    = (const float*)d_in[3];
    const float* base_B    = (const float*)d_in[4];
    const float* sub_wgate = (const float*)d_in[5];
    const float* sub_A     = (const float*)d_in[6];
    const float* sub_B     = (const float*)d_in[7];
    float* out = (float*)d_out;

    // workspace layout (bf16): X_cat [8192][4160], W_cat [4096][4160], Vc [80][4096]
    unsigned short* Xc = (unsigned short*)d_ws;
    unsigned short* Wc = Xc + (size_t)MTOT * LDK;
    unsigned short* Vc = Wc + (size_t)DOUT * LDK;

    prep_kernel<<<2048 + NV + 2048, 256, 0, stream>>>(
        x, Xc, sub_wgate, sub_A, Vc, base_W, base_A, base_B, sub_B, Wc);
    xtail_kernel<<<MTOT / 32, 256, 0, stream>>>(Vc, Xc);
    gemm_kernel<<<dim3(DOUT / 256 * (MTOT / 256)), 512, 0, stream>>>(Xc, Wc, base_b, out);
}